// Round 1
// baseline (2122.497 us; speedup 1.0000x reference)
//
#include <hip/hip_runtime.h>
#include <cstdint>
#include <cstddef>

// ---------------------------------------------------------------------------
// 4-layer GCN, fp32 baseline.
// Pipeline per layer: GEMM (h = in @ W) -> agg init (bias + self-loop) ->
// edge scatter (atomicAdd) -> ReLU (layers 1-3).  Final: log_softmax.
// ---------------------------------------------------------------------------

// ---------------- edge-index dtype detection -------------------------------
__global__ void k_flag_init(int* flag) {
    if (blockIdx.x == 0 && threadIdx.x == 0) *flag = 1;
}

// Interpret first E entries as int64; any out-of-range => data is int32.
__global__ void k_flag_check(const long long* __restrict__ p, int E, long long N,
                             int* flag) {
    long long i = (long long)blockIdx.x * blockDim.x + threadIdx.x;
    long long stride = (long long)gridDim.x * blockDim.x;
    for (; i < E; i += stride) {
        long long v = p[i];
        if (v < 0 || v >= N) *flag = 0;   // racy same-value store: fine
    }
}

// ---------------- degree / norm --------------------------------------------
__global__ void k_fill1(float* __restrict__ deg, int N) {
    int i = blockIdx.x * blockDim.x + threadIdx.x;
    if (i < N) deg[i] = 1.0f;             // self-loop contribution
}

__global__ void k_deg(const void* __restrict__ eidx, const int* __restrict__ flag,
                      float* __restrict__ deg, int E) {
    int i = blockIdx.x * blockDim.x + threadIdx.x;
    if (i >= E) return;
    int fl = *flag;
    long long d = fl ? ((const long long*)eidx)[E + i]
                     : (long long)((const int*)eidx)[E + i];
    atomicAdd(&deg[d], 1.0f);
}

__global__ void k_dinv(float* __restrict__ deg, int N) {
    int i = blockIdx.x * blockDim.x + threadIdx.x;
    if (i < N) deg[i] = rsqrtf(deg[i]);   // deg >= 1 always (self-loops)
}

// ---------------- fp32 tiled GEMM: C[M,N] = A[M,K] @ B[K,N] ----------------
__global__ __launch_bounds__(256) void k_gemm(const float* __restrict__ A,
                                              const float* __restrict__ B,
                                              float* __restrict__ C,
                                              int M, int N, int K) {
    __shared__ float sA[16][68];   // [k][m], pad to dodge bank conflicts
    __shared__ float sB[16][64];   // [k][n]
    int tid = threadIdx.x;
    int tx = tid & 15, ty = tid >> 4;
    int row0 = blockIdx.y * 64, col0 = blockIdx.x * 64;
    float acc[4][4] = {};

    for (int k0 = 0; k0 < K; k0 += 16) {
        // A tile 64x16: thread t loads (m = idx>>4, k = idx&15) -> contiguous k
#pragma unroll
        for (int i = 0; i < 4; i++) {
            int idx = tid + i * 256;
            int m = idx >> 4, k = idx & 15;
            int row = row0 + m, kk = k0 + k;
            sA[k][m] = (row < M && kk < K) ? A[(long long)row * K + kk] : 0.0f;
        }
        // B tile 16x64: (n = idx&63, k = idx>>6) -> contiguous n (coalesced)
#pragma unroll
        for (int i = 0; i < 4; i++) {
            int idx = tid + i * 256;
            int n = idx & 63, k = idx >> 6;
            int col = col0 + n, kk = k0 + k;
            sB[k][n] = (kk < K && col < N) ? B[(long long)kk * N + col] : 0.0f;
        }
        __syncthreads();
#pragma unroll
        for (int k = 0; k < 16; k++) {
            float a[4], b[4];
#pragma unroll
            for (int i = 0; i < 4; i++) a[i] = sA[k][ty * 4 + i];
#pragma unroll
            for (int j = 0; j < 4; j++) b[j] = sB[k][tx * 4 + j];
#pragma unroll
            for (int i = 0; i < 4; i++)
#pragma unroll
                for (int j = 0; j < 4; j++) acc[i][j] += a[i] * b[j];
        }
        __syncthreads();
    }
#pragma unroll
    for (int i = 0; i < 4; i++) {
        int row = row0 + ty * 4 + i;
        if (row >= M) continue;
#pragma unroll
        for (int j = 0; j < 4; j++) {
            int col = col0 + tx * 4 + j;
            if (col < N) C[(long long)row * N + col] = acc[i][j];
        }
    }
}

// ---------------- aggregation ----------------------------------------------
// out[i,f] = b[f] + h[i,f] * dinv[i]^2   (self-loop + bias init)
__global__ __launch_bounds__(256) void k_agg_init(const float* __restrict__ h,
                                                  const float* __restrict__ dinv,
                                                  const float* __restrict__ bias,
                                                  float* __restrict__ out, int H) {
    int i = blockIdx.x;
    int f = threadIdx.x;
    if (f < H) {
        float di = dinv[i];
        out[(long long)i * H + f] = bias[f] + h[(long long)i * H + f] * di * di;
    }
}

// one wave per edge: out[dst,:] += h[src,:] * dinv[src]*dinv[dst]
__global__ __launch_bounds__(256) void k_scatter(const void* __restrict__ eidx,
                                                 const int* __restrict__ flag,
                                                 const float* __restrict__ h,
                                                 const float* __restrict__ dinv,
                                                 float* __restrict__ out,
                                                 int E, int H) {
    int w = (int)(((long long)blockIdx.x * blockDim.x + threadIdx.x) >> 6);
    if (w >= E) return;
    int lane = threadIdx.x & 63;
    int fl = *flag;
    long long s, d;
    if (fl) {
        s = ((const long long*)eidx)[w];
        d = ((const long long*)eidx)[E + w];
    } else {
        s = (long long)((const int*)eidx)[w];
        d = (long long)((const int*)eidx)[E + w];
    }
    float nrm = dinv[s] * dinv[d];
    const float* hs = h + s * (long long)H;
    float* od = out + d * (long long)H;
    for (int f = lane; f < H; f += 64) atomicAdd(&od[f], hs[f] * nrm);
}

__global__ void k_relu(float* __restrict__ x, long long n) {
    long long i = (long long)blockIdx.x * blockDim.x + threadIdx.x;
    long long stride = (long long)gridDim.x * blockDim.x;
    for (; i < n; i += stride) x[i] = fmaxf(x[i], 0.0f);
}

// ---------------- log_softmax over H cols, one block per row ---------------
__global__ __launch_bounds__(256) void k_logsoftmax(const float* __restrict__ in,
                                                    float* __restrict__ out, int H) {
    __shared__ float red[8];
    int i = blockIdx.x;
    int tid = threadIdx.x;
    int wave = tid >> 6;
    float v = (tid < H) ? in[(long long)i * H + tid] : -INFINITY;

    float m = v;
#pragma unroll
    for (int off = 32; off > 0; off >>= 1) m = fmaxf(m, __shfl_xor(m, off));
    if ((tid & 63) == 0) red[wave] = m;
    __syncthreads();
    if (tid == 0)
        red[4] = fmaxf(fmaxf(red[0], red[1]), fmaxf(red[2], red[3]));
    __syncthreads();
    m = red[4];

    float e = (tid < H) ? __expf(v - m) : 0.0f;
    float s = e;
#pragma unroll
    for (int off = 32; off > 0; off >>= 1) s += __shfl_xor(s, off);
    if ((tid & 63) == 0) red[wave] = s;
    __syncthreads();
    if (tid == 0) red[5] = red[0] + red[1] + red[2] + red[3];
    __syncthreads();
    float lse = m + logf(red[5]);
    if (tid < H) out[(long long)i * H + tid] = v - lse;
}

// ---------------------------------------------------------------------------
extern "C" void kernel_launch(void* const* d_in, const int* in_sizes, int n_in,
                              void* d_out, int out_size, void* d_ws, size_t ws_size,
                              hipStream_t stream) {
    const float* x    = (const float*)d_in[0];
    const void*  eidx = d_in[1];
    const float* W[4] = {(const float*)d_in[2], (const float*)d_in[4],
                         (const float*)d_in[6], (const float*)d_in[8]};
    const float* b[4] = {(const float*)d_in[3], (const float*)d_in[5],
                         (const float*)d_in[7], (const float*)d_in[9]};

    const int H   = in_sizes[3];          // 246
    const int E   = in_sizes[1] / 2;      // 320000
    const int FIN = in_sizes[2] / H;      // 256
    const int N   = in_sizes[0] / FIN;    // 50000

    char* ws = (char*)d_ws;
    int*   flag = (int*)ws;
    size_t o_dinv = 256;
    size_t dinvB  = (((size_t)N * 4) + 255) / 256 * 256;
    size_t bufB_  = (((size_t)N * H * 4) + 255) / 256 * 256;
    float* dinv = (float*)(ws + o_dinv);
    float* bufA = (float*)(ws + o_dinv + dinvB);
    float* bufB = (float*)(ws + o_dinv + dinvB + bufB_);

    // --- edge dtype detection + degree/norm ---
    k_flag_init<<<1, 64, 0, stream>>>(flag);
    k_flag_check<<<512, 256, 0, stream>>>((const long long*)eidx, E, (long long)N, flag);
    k_fill1<<<(N + 255) / 256, 256, 0, stream>>>(dinv, N);
    k_deg<<<(E + 255) / 256, 256, 0, stream>>>(eidx, flag, dinv, E);
    k_dinv<<<(N + 255) / 256, 256, 0, stream>>>(dinv, N);

    dim3 gemm_grid((H + 63) / 64, (N + 63) / 64);
    int scat_blocks = (E * 4 + 3) / 4 / 1;      // E waves, 4 waves/block
    scat_blocks = (E + 3) / 4;

    // --- layer 1: in = x (K=FIN) ---
    k_gemm<<<gemm_grid, 256, 0, stream>>>(x, W[0], bufA, N, H, FIN);
    k_agg_init<<<N, 256, 0, stream>>>(bufA, dinv, b[0], bufB, H);
    k_scatter<<<scat_blocks, 256, 0, stream>>>(eidx, flag, bufA, dinv, bufB, E, H);
    k_relu<<<2048, 256, 0, stream>>>(bufB, (long long)N * H);

    // --- layers 2,3: in = bufB (K=H) ---
    for (int l = 1; l <= 2; l++) {
        k_gemm<<<gemm_grid, 256, 0, stream>>>(bufB, W[l], bufA, N, H, H);
        k_agg_init<<<N, 256, 0, stream>>>(bufA, dinv, b[l], bufB, H);
        k_scatter<<<scat_blocks, 256, 0, stream>>>(eidx, flag, bufA, dinv, bufB, E, H);
        k_relu<<<2048, 256, 0, stream>>>(bufB, (long long)N * H);
    }

    // --- layer 4 (no relu) + log_softmax ---
    k_gemm<<<gemm_grid, 256, 0, stream>>>(bufB, W[3], bufA, N, H, H);
    k_agg_init<<<N, 256, 0, stream>>>(bufA, dinv, b[3], bufB, H);
    k_scatter<<<scat_blocks, 256, 0, stream>>>(eidx, flag, bufA, dinv, bufB, E, H);
    k_logsoftmax<<<N, 256, 0, stream>>>(bufB, (float*)d_out, H);
}

// Round 2
// 1135.821 us; speedup vs baseline: 1.8687x; 1.8687x over previous
//
#include <hip/hip_runtime.h>
#include <cstdint>
#include <cstddef>

// ---------------------------------------------------------------------------
// 4-layer GCN. Round 2: scatter -> CSR gather (atomic-free aggregation).
// Pipeline: detect edge dtype -> count/scan/fill CSR (once) -> per layer:
// GEMM (fp32 tiled) -> gather (self-loop + edges + bias + relu) -> final
// log_softmax.
// ---------------------------------------------------------------------------

// ---------------- edge-index dtype detection -------------------------------
__global__ void k_flag_init(int* flag) {
    if (blockIdx.x == 0 && threadIdx.x == 0) *flag = 1;
}

// Interpret first E entries as int64; any out-of-range => data is int32.
__global__ void k_flag_check(const long long* __restrict__ p, int E, long long N,
                             int* flag) {
    long long i = (long long)blockIdx.x * blockDim.x + threadIdx.x;
    long long stride = (long long)gridDim.x * blockDim.x;
    for (; i < E; i += stride) {
        long long v = p[i];
        if (v < 0 || v >= N) *flag = 0;   // racy same-value store: fine
    }
}

__device__ __forceinline__ void load_edge(const void* eidx, int fl, int E, int i,
                                          int& s, int& d) {
    if (fl) {
        s = (int)((const long long*)eidx)[i];
        d = (int)((const long long*)eidx)[E + i];
    } else {
        s = ((const int*)eidx)[i];
        d = ((const int*)eidx)[E + i];
    }
}

// ---------------- CSR build -------------------------------------------------
__global__ void k_zero_i32(int* __restrict__ p, int n) {
    int i = blockIdx.x * blockDim.x + threadIdx.x;
    if (i < n) p[i] = 0;
}

__global__ void k_count(const void* __restrict__ eidx, const int* __restrict__ flag,
                        int* __restrict__ counts, int E) {
    int i = blockIdx.x * blockDim.x + threadIdx.x;
    if (i >= E) return;
    int s, d;
    load_edge(eidx, *flag, E, i, s, d);
    atomicAdd(&counts[d], 1);
}

// dinv = rsqrt(in_degree + 1)   (self-loop => deg >= 1)
__global__ void k_dinv(const int* __restrict__ counts, float* __restrict__ dinv,
                       int N) {
    int i = blockIdx.x * blockDim.x + threadIdx.x;
    if (i < N) dinv[i] = rsqrtf((float)counts[i] + 1.0f);
}

// single-block exclusive scan of counts -> starts[0..N], starts[N] = E
__global__ __launch_bounds__(1024) void k_scan(const int* __restrict__ counts,
                                               int* __restrict__ starts, int N) {
    __shared__ int wsum[16];
    __shared__ int wscan[16];
    __shared__ int s_carry;
    int tid = threadIdx.x;
    int lane = tid & 63, wid = tid >> 6;
    if (tid == 0) s_carry = 0;
    __syncthreads();
    for (int base = 0; base < N; base += 1024) {
        int i = base + tid;
        int v = (i < N) ? counts[i] : 0;
        // wave-level inclusive scan (no LDS)
        int incl = v;
#pragma unroll
        for (int off = 1; off < 64; off <<= 1) {
            int t = __shfl_up(incl, off);
            if (lane >= off) incl += t;
        }
        if (lane == 63) wsum[wid] = incl;
        __syncthreads();
        if (wid == 0 && lane < 16) {
            int w = wsum[lane];
#pragma unroll
            for (int off = 1; off < 16; off <<= 1) {
                int t = __shfl_up(w, off);
                if (lane >= off) w += t;
            }
            wscan[lane] = w;
        }
        __syncthreads();
        int woff = (wid > 0) ? wscan[wid - 1] : 0;
        int excl = s_carry + woff + incl - v;
        if (i < N) starts[i] = excl;
        int total = wscan[15];
        __syncthreads();
        if (tid == 0) s_carry += total;
        __syncthreads();
    }
    if (tid == 0) starts[N] = s_carry;
}

__global__ void k_copy_i32(const int* __restrict__ a, int* __restrict__ b, int n) {
    int i = blockIdx.x * blockDim.x + threadIdx.x;
    if (i < n) b[i] = a[i];
}

__global__ void k_fill(const void* __restrict__ eidx, const int* __restrict__ flag,
                       int* __restrict__ cursor, int* __restrict__ srcs, int E) {
    int i = blockIdx.x * blockDim.x + threadIdx.x;
    if (i >= E) return;
    int s, d;
    load_edge(eidx, *flag, E, i, s, d);
    int pos = atomicAdd(&cursor[d], 1);
    srcs[pos] = s;
}

// ---------------- fp32 tiled GEMM: C[M,N] = A[M,K] @ B[K,N] ----------------
__global__ __launch_bounds__(256) void k_gemm(const float* __restrict__ A,
                                              const float* __restrict__ B,
                                              float* __restrict__ C,
                                              int M, int N, int K) {
    __shared__ float sA[16][68];
    __shared__ float sB[16][64];
    int tid = threadIdx.x;
    int tx = tid & 15, ty = tid >> 4;
    int row0 = blockIdx.y * 64, col0 = blockIdx.x * 64;
    float acc[4][4] = {};

    for (int k0 = 0; k0 < K; k0 += 16) {
#pragma unroll
        for (int i = 0; i < 4; i++) {
            int idx = tid + i * 256;
            int m = idx >> 4, k = idx & 15;
            int row = row0 + m, kk = k0 + k;
            sA[k][m] = (row < M && kk < K) ? A[(long long)row * K + kk] : 0.0f;
        }
#pragma unroll
        for (int i = 0; i < 4; i++) {
            int idx = tid + i * 256;
            int n = idx & 63, k = idx >> 6;
            int col = col0 + n, kk = k0 + k;
            sB[k][n] = (kk < K && col < N) ? B[(long long)kk * N + col] : 0.0f;
        }
        __syncthreads();
#pragma unroll
        for (int k = 0; k < 16; k++) {
            float a[4], b[4];
#pragma unroll
            for (int i = 0; i < 4; i++) a[i] = sA[k][ty * 4 + i];
#pragma unroll
            for (int j = 0; j < 4; j++) b[j] = sB[k][tx * 4 + j];
#pragma unroll
            for (int i = 0; i < 4; i++)
#pragma unroll
                for (int j = 0; j < 4; j++) acc[i][j] += a[i] * b[j];
        }
        __syncthreads();
    }
#pragma unroll
    for (int i = 0; i < 4; i++) {
        int row = row0 + ty * 4 + i;
        if (row >= M) continue;
#pragma unroll
        for (int j = 0; j < 4; j++) {
            int col = col0 + tx * 4 + j;
            if (col < N) C[(long long)row * N + col] = acc[i][j];
        }
    }
}

// ---------------- CSR gather aggregation -----------------------------------
// out[d,f] = relu?( dinv[d] * ( h[d,f]*dinv[d] + sum_{s in N(d)} h[s,f]*dinv[s] )
//                   + bias[f] )
__global__ __launch_bounds__(256) void k_gather(const float* __restrict__ h,
                                                const int* __restrict__ srcs,
                                                const int* __restrict__ starts,
                                                const float* __restrict__ dinv,
                                                const float* __restrict__ bias,
                                                float* __restrict__ out,
                                                int H, int relu) {
    int d = blockIdx.x;
    int f = threadIdx.x;
    float dd = dinv[d];
    int e0 = starts[d], e1 = starts[d + 1];
    bool act = (f < H);
    float acc = act ? h[(long long)d * H + f] * dd : 0.0f;   // self-loop (pre-×dd)
    int e = e0;
    for (; e + 1 < e1; e += 2) {                              // 2-deep ILP
        int s0 = srcs[e], s1 = srcs[e + 1];
        float n0 = dinv[s0], n1 = dinv[s1];
        float v0 = act ? h[(long long)s0 * H + f] : 0.0f;
        float v1 = act ? h[(long long)s1 * H + f] : 0.0f;
        acc += v0 * n0 + v1 * n1;
    }
    if (e < e1) {
        int s0 = srcs[e];
        float v0 = act ? h[(long long)s0 * H + f] : 0.0f;
        acc += v0 * dinv[s0];
    }
    if (act) {
        float v = acc * dd + bias[f];
        if (relu) v = fmaxf(v, 0.0f);
        out[(long long)d * H + f] = v;
    }
}

// ---------------- log_softmax over H cols, one block per row ---------------
__global__ __launch_bounds__(256) void k_logsoftmax(const float* __restrict__ in,
                                                    float* __restrict__ out, int H) {
    __shared__ float red[8];
    int i = blockIdx.x;
    int tid = threadIdx.x;
    int wave = tid >> 6;
    float v = (tid < H) ? in[(long long)i * H + tid] : -INFINITY;

    float m = v;
#pragma unroll
    for (int off = 32; off > 0; off >>= 1) m = fmaxf(m, __shfl_xor(m, off));
    if ((tid & 63) == 0) red[wave] = m;
    __syncthreads();
    if (tid == 0)
        red[4] = fmaxf(fmaxf(red[0], red[1]), fmaxf(red[2], red[3]));
    __syncthreads();
    m = red[4];

    float e = (tid < H) ? __expf(v - m) : 0.0f;
    float s = e;
#pragma unroll
    for (int off = 32; off > 0; off >>= 1) s += __shfl_xor(s, off);
    if ((tid & 63) == 0) red[wave] = s;
    __syncthreads();
    if (tid == 0) red[5] = red[0] + red[1] + red[2] + red[3];
    __syncthreads();
    float lse = m + logf(red[5]);
    if (tid < H) out[(long long)i * H + tid] = v - lse;
}

// ---------------------------------------------------------------------------
extern "C" void kernel_launch(void* const* d_in, const int* in_sizes, int n_in,
                              void* d_out, int out_size, void* d_ws, size_t ws_size,
                              hipStream_t stream) {
    const float* x    = (const float*)d_in[0];
    const void*  eidx = d_in[1];
    const float* W[4] = {(const float*)d_in[2], (const float*)d_in[4],
                         (const float*)d_in[6], (const float*)d_in[8]};
    const float* b[4] = {(const float*)d_in[3], (const float*)d_in[5],
                         (const float*)d_in[7], (const float*)d_in[9]};

    const int H   = in_sizes[3];          // 246
    const int E   = in_sizes[1] / 2;      // 320000
    const int FIN = in_sizes[2] / H;      // 256
    const int N   = in_sizes[0] / FIN;    // 50000

    auto align = [](size_t v) { return (v + 255) / 256 * 256; };
    char* ws = (char*)d_ws;
    size_t off = 0;
    int* flag = (int*)(ws + off);             off += 256;
    float* dinv = (float*)(ws + off);         off += align((size_t)N * 4);
    int* counts = (int*)(ws + off);           off += align((size_t)N * 4);   // reused as cursor
    int* starts = (int*)(ws + off);           off += align((size_t)(N + 1) * 4);
    int* srcs = (int*)(ws + off);             off += align((size_t)E * 4);
    float* bufA = (float*)(ws + off);         off += align((size_t)N * H * 4);
    float* bufB = (float*)(ws + off);         off += align((size_t)N * H * 4);

    int nb = (N + 255) / 256, eb = (E + 255) / 256;

    // --- edge dtype detection ---
    k_flag_init<<<1, 64, 0, stream>>>(flag);
    k_flag_check<<<512, 256, 0, stream>>>((const long long*)eidx, E, (long long)N, flag);

    // --- CSR build (once, reused all 4 layers) ---
    k_zero_i32<<<nb, 256, 0, stream>>>(counts, N);
    k_count<<<eb, 256, 0, stream>>>(eidx, flag, counts, E);
    k_dinv<<<nb, 256, 0, stream>>>(counts, dinv, N);
    k_scan<<<1, 1024, 0, stream>>>(counts, starts, N);
    k_copy_i32<<<nb, 256, 0, stream>>>(starts, counts, N);   // counts := cursor
    k_fill<<<eb, 256, 0, stream>>>(eidx, flag, counts, srcs, E);

    dim3 gemm_grid((H + 63) / 64, (N + 63) / 64);

    // --- layer 1 (K=FIN) ---
    k_gemm<<<gemm_grid, 256, 0, stream>>>(x, W[0], bufA, N, H, FIN);
    k_gather<<<N, 256, 0, stream>>>(bufA, srcs, starts, dinv, b[0], bufB, H, 1);

    // --- layers 2,3 (K=H) ---
    for (int l = 1; l <= 2; l++) {
        k_gemm<<<gemm_grid, 256, 0, stream>>>(bufB, W[l], bufA, N, H, H);
        k_gather<<<N, 256, 0, stream>>>(bufA, srcs, starts, dinv, b[l], bufB, H, 1);
    }

    // --- layer 4 (no relu) + log_softmax ---
    k_gemm<<<gemm_grid, 256, 0, stream>>>(bufB, W[3], bufA, N, H, H);
    k_gather<<<N, 256, 0, stream>>>(bufA, srcs, starts, dinv, b[3], bufB, H, 0);
    k_logsoftmax<<<N, 256, 0, stream>>>(bufB, (float*)d_out, H);
}

// Round 3
// 757.660 us; speedup vs baseline: 2.8014x; 1.4991x over previous
//
#include <hip/hip_runtime.h>
#include <cstdint>
#include <cstddef>

// ---------------------------------------------------------------------------
// 4-layer GCN. Round 3: fp32 GEMM -> split-bf16 (hi+lo) MFMA GEMM, 3 passes
// per k-step => fp32-grade accuracy at matrix-core rate. CSR gather epilogue
// emits bf16 hi/lo directly for the next layer's GEMM.
// ---------------------------------------------------------------------------

typedef __bf16 bf16x8 __attribute__((ext_vector_type(8)));
typedef float f32x4 __attribute__((ext_vector_type(4)));

__device__ __forceinline__ unsigned short f2bf(float v) {   // RNE
    union { float f; unsigned u; } x; x.f = v;
    unsigned r = x.u + 0x7fff + ((x.u >> 16) & 1);
    return (unsigned short)(r >> 16);
}
__device__ __forceinline__ float bf2f(unsigned short h) {
    union { unsigned u; float f; } x; x.u = (unsigned)h << 16; return x.f;
}

// ---------------- edge-index dtype detection -------------------------------
__global__ void k_flag_init(int* flag) {
    if (blockIdx.x == 0 && threadIdx.x == 0) *flag = 1;
}

__global__ void k_flag_check(const long long* __restrict__ p, int E, long long N,
                             int* flag) {
    long long i = (long long)blockIdx.x * blockDim.x + threadIdx.x;
    long long stride = (long long)gridDim.x * blockDim.x;
    for (; i < E; i += stride) {
        long long v = p[i];
        if (v < 0 || v >= N) *flag = 0;
    }
}

__device__ __forceinline__ void load_edge(const void* eidx, int fl, int E, int i,
                                          int& s, int& d) {
    if (fl) {
        s = (int)((const long long*)eidx)[i];
        d = (int)((const long long*)eidx)[E + i];
    } else {
        s = ((const int*)eidx)[i];
        d = ((const int*)eidx)[E + i];
    }
}

// ---------------- CSR build -------------------------------------------------
__global__ void k_zero_i32(int* __restrict__ p, int n) {
    int i = blockIdx.x * blockDim.x + threadIdx.x;
    if (i < n) p[i] = 0;
}

__global__ void k_count(const void* __restrict__ eidx, const int* __restrict__ flag,
                        int* __restrict__ counts, int E) {
    int i = blockIdx.x * blockDim.x + threadIdx.x;
    if (i >= E) return;
    int s, d;
    load_edge(eidx, *flag, E, i, s, d);
    atomicAdd(&counts[d], 1);
}

__global__ void k_dinv(const int* __restrict__ counts, float* __restrict__ dinv,
                       int N) {
    int i = blockIdx.x * blockDim.x + threadIdx.x;
    if (i < N) dinv[i] = rsqrtf((float)counts[i] + 1.0f);
}

__global__ __launch_bounds__(1024) void k_scan(const int* __restrict__ counts,
                                               int* __restrict__ starts, int N) {
    __shared__ int wsum[16];
    __shared__ int wscan[16];
    __shared__ int s_carry;
    int tid = threadIdx.x;
    int lane = tid & 63, wid = tid >> 6;
    if (tid == 0) s_carry = 0;
    __syncthreads();
    for (int base = 0; base < N; base += 1024) {
        int i = base + tid;
        int v = (i < N) ? counts[i] : 0;
        int incl = v;
#pragma unroll
        for (int off = 1; off < 64; off <<= 1) {
            int t = __shfl_up(incl, off);
            if (lane >= off) incl += t;
        }
        if (lane == 63) wsum[wid] = incl;
        __syncthreads();
        if (wid == 0 && lane < 16) {
            int w = wsum[lane];
#pragma unroll
            for (int off = 1; off < 16; off <<= 1) {
                int t = __shfl_up(w, off);
                if (lane >= off) w += t;
            }
            wscan[lane] = w;
        }
        __syncthreads();
        int woff = (wid > 0) ? wscan[wid - 1] : 0;
        int excl = s_carry + woff + incl - v;
        if (i < N) starts[i] = excl;
        int total = wscan[15];
        __syncthreads();
        if (tid == 0) s_carry += total;
        __syncthreads();
    }
    if (tid == 0) starts[N] = s_carry;
}

__global__ void k_copy_i32(const int* __restrict__ a, int* __restrict__ b, int n) {
    int i = blockIdx.x * blockDim.x + threadIdx.x;
    if (i < n) b[i] = a[i];
}

__global__ void k_fill(const void* __restrict__ eidx, const int* __restrict__ flag,
                       int* __restrict__ cursor, int* __restrict__ srcs, int E) {
    int i = blockIdx.x * blockDim.x + threadIdx.x;
    if (i >= E) return;
    int s, d;
    load_edge(eidx, *flag, E, i, s, d);
    int pos = atomicAdd(&cursor[d], 1);
    srcs[pos] = s;
}

// ---------------- fp32 -> bf16 hi/lo conversions ---------------------------
__global__ void k_cvt_x(const float* __restrict__ x, unsigned short* __restrict__ hi,
                        unsigned short* __restrict__ lo, long long n) {
    long long i = (long long)blockIdx.x * blockDim.x + threadIdx.x;
    long long stride = (long long)gridDim.x * blockDim.x;
    for (; i < n; i += stride) {
        float v = x[i];
        unsigned short h = f2bf(v);
        hi[i] = h;
        lo[i] = f2bf(v - bf2f(h));
    }
}

// W [K][H] fp32 -> transposed, padded [256][256] bf16 hi/lo (zeros outside)
__global__ void k_cvt_w(const float* __restrict__ W, unsigned short* __restrict__ Thi,
                        unsigned short* __restrict__ Tlo, int K, int H) {
    int idx = blockIdx.x * blockDim.x + threadIdx.x;
    if (idx >= 256 * 256) return;
    int k = idx & 255, n = idx >> 8;
    float v = (k < K && n < H) ? W[k * H + n] : 0.0f;
    unsigned short h = f2bf(v);
    Thi[n * 256 + k] = h;
    Tlo[n * 256 + k] = f2bf(v - bf2f(h));
}

// ---------------- split-bf16 MFMA GEMM -------------------------------------
// C[M][H] = A[M][256] @ W[256][H], A given as hi/lo bf16 [M][256] (zero-padded
// cols >= K), W given transposed hi/lo [256][256]. 128x128 tile, 4 waves,
// each wave 64x64 via 4x4 grid of 16x16x32 MFMA; 3 passes (hh, lh, hl).
__global__ __launch_bounds__(256) void k_gemm_mfma(
        const unsigned short* __restrict__ Ahi, const unsigned short* __restrict__ Alo,
        const unsigned short* __restrict__ BThi, const unsigned short* __restrict__ BTlo,
        float* __restrict__ C, int M, int H) {
    // LDS: [hl][kq][m][8] bf16 for A, same with n for B.  16 KB + 16 KB.
    __shared__ unsigned short ldsA[2 * 4 * 128 * 8];
    __shared__ unsigned short ldsB[2 * 4 * 128 * 8];

    int tid = threadIdx.x;
    int lane = tid & 63;
    int w = tid >> 6;
    int wm = (w & 1) * 64, wn = (w >> 1) * 64;
    int kq = lane >> 4, lr = lane & 15;
    int row0 = blockIdx.y * 128, col0 = blockIdx.x * 128;

    f32x4 acc[4][4] = {};

    for (int k0 = 0; k0 < 256; k0 += 32) {
        __syncthreads();
        // stage A: 1024 chunks of 16B  (idx: m fastest->coalesced-by-4, kq next)
#pragma unroll
        for (int i = 0; i < 4; i++) {
            int idx = tid + i * 256;
            int hl = idx >> 9;
            int rem = idx & 511;
            int kqq = rem & 3;
            int m = rem >> 2;
            int row = row0 + m;
            uint4 v = {0, 0, 0, 0};
            if (row < M) {
                const unsigned short* src = (hl ? Alo : Ahi) + (((long long)row) << 8)
                                            + k0 + kqq * 8;
                v = *(const uint4*)src;
            }
            *(uint4*)&ldsA[((hl * 4 + kqq) * 128 + m) * 8] = v;
        }
        // stage B (always in-bounds: padded 256x256)
#pragma unroll
        for (int i = 0; i < 4; i++) {
            int idx = tid + i * 256;
            int hl = idx >> 9;
            int rem = idx & 511;
            int kqq = rem & 3;
            int n = rem >> 2;
            const unsigned short* src = (hl ? BTlo : BThi)
                                        + (((long long)(col0 + n)) << 8) + k0 + kqq * 8;
            *(uint4*)&ldsB[((hl * 4 + kqq) * 128 + n) * 8] = *(const uint4*)src;
        }
        __syncthreads();

        bf16x8 ah[4], al[4], bh[4], bl[4];
#pragma unroll
        for (int t = 0; t < 4; t++) {
            int m = wm + t * 16 + lr;
            ah[t] = *(const bf16x8*)&ldsA[((0 * 4 + kq) * 128 + m) * 8];
            al[t] = *(const bf16x8*)&ldsA[((1 * 4 + kq) * 128 + m) * 8];
            int n = wn + t * 16 + lr;
            bh[t] = *(const bf16x8*)&ldsB[((0 * 4 + kq) * 128 + n) * 8];
            bl[t] = *(const bf16x8*)&ldsB[((1 * 4 + kq) * 128 + n) * 8];
        }
#pragma unroll
        for (int mt = 0; mt < 4; mt++)
#pragma unroll
            for (int nt = 0; nt < 4; nt++) {
                acc[mt][nt] = __builtin_amdgcn_mfma_f32_16x16x32_bf16(
                    ah[mt], bh[nt], acc[mt][nt], 0, 0, 0);
                acc[mt][nt] = __builtin_amdgcn_mfma_f32_16x16x32_bf16(
                    al[mt], bh[nt], acc[mt][nt], 0, 0, 0);
                acc[mt][nt] = __builtin_amdgcn_mfma_f32_16x16x32_bf16(
                    ah[mt], bl[nt], acc[mt][nt], 0, 0, 0);
            }
    }

    // epilogue: C/D layout col=lane&15, row=(lane>>4)*4+reg  [m89-verified]
#pragma unroll
    for (int mt = 0; mt < 4; mt++) {
#pragma unroll
        for (int nt = 0; nt < 4; nt++) {
            int col = col0 + wn + nt * 16 + lr;
            int rowb = row0 + wm + mt * 16 + kq * 4;
            if (col < H) {
#pragma unroll
                for (int r = 0; r < 4; r++) {
                    int row = rowb + r;
                    if (row < M) C[(long long)row * H + col] = acc[mt][nt][r];
                }
            }
        }
    }
}

// ---------------- CSR gather aggregation -----------------------------------
// out = relu?( dinv[d]*( h[d]*dinv[d] + sum_s h[s]*dinv[s] ) + bias )
// writes bf16 hi/lo (stride 256, zero-padded) and/or fp32 (stride H)
__global__ __launch_bounds__(256) void k_gather(const float* __restrict__ h,
                                                const int* __restrict__ srcs,
                                                const int* __restrict__ starts,
                                                const float* __restrict__ dinv,
                                                const float* __restrict__ bias,
                                                unsigned short* __restrict__ out_hi,
                                                unsigned short* __restrict__ out_lo,
                                                float* __restrict__ out_f32,
                                                int H, int relu) {
    int d = blockIdx.x;
    int f = threadIdx.x;
    float dd = dinv[d];
    int e0 = starts[d], e1 = starts[d + 1];
    bool act = (f < H);
    float acc = act ? h[(long long)d * H + f] * dd : 0.0f;
    int e = e0;
    for (; e + 1 < e1; e += 2) {
        int s0 = srcs[e], s1 = srcs[e + 1];
        float n0 = dinv[s0], n1 = dinv[s1];
        float v0 = act ? h[(long long)s0 * H + f] : 0.0f;
        float v1 = act ? h[(long long)s1 * H + f] : 0.0f;
        acc += v0 * n0 + v1 * n1;
    }
    if (e < e1) {
        int s0 = srcs[e];
        float v0 = act ? h[(long long)s0 * H + f] : 0.0f;
        acc += v0 * dinv[s0];
    }
    if (act) {
        float v = acc * dd + bias[f];
        if (relu) v = fmaxf(v, 0.0f);
        if (out_f32) out_f32[(long long)d * H + f] = v;
        if (out_hi) {
            unsigned short hi = f2bf(v);
            out_hi[(long long)d * 256 + f] = hi;
            out_lo[(long long)d * 256 + f] = f2bf(v - bf2f(hi));
        }
    } else if (out_hi) {       // zero-pad cols H..255
        out_hi[(long long)d * 256 + f] = 0;
        out_lo[(long long)d * 256 + f] = 0;
    }
}

// ---------------- log_softmax over H cols ----------------------------------
__global__ __launch_bounds__(256) void k_logsoftmax(const float* __restrict__ in,
                                                    float* __restrict__ out, int H) {
    __shared__ float red[8];
    int i = blockIdx.x;
    int tid = threadIdx.x;
    int wave = tid >> 6;
    float v = (tid < H) ? in[(long long)i * H + tid] : -INFINITY;

    float m = v;
#pragma unroll
    for (int off = 32; off > 0; off >>= 1) m = fmaxf(m, __shfl_xor(m, off));
    if ((tid & 63) == 0) red[wave] = m;
    __syncthreads();
    if (tid == 0)
        red[4] = fmaxf(fmaxf(red[0], red[1]), fmaxf(red[2], red[3]));
    __syncthreads();
    m = red[4];

    float e = (tid < H) ? __expf(v - m) : 0.0f;
    float s = e;
#pragma unroll
    for (int off = 32; off > 0; off >>= 1) s += __shfl_xor(s, off);
    if ((tid & 63) == 0) red[wave] = s;
    __syncthreads();
    if (tid == 0) red[5] = red[0] + red[1] + red[2] + red[3];
    __syncthreads();
    float lse = m + logf(red[5]);
    if (tid < H) out[(long long)i * H + tid] = v - lse;
}

// ---------------------------------------------------------------------------
extern "C" void kernel_launch(void* const* d_in, const int* in_sizes, int n_in,
                              void* d_out, int out_size, void* d_ws, size_t ws_size,
                              hipStream_t stream) {
    const float* x    = (const float*)d_in[0];
    const void*  eidx = d_in[1];
    const float* W[4] = {(const float*)d_in[2], (const float*)d_in[4],
                         (const float*)d_in[6], (const float*)d_in[8]};
    const float* b[4] = {(const float*)d_in[3], (const float*)d_in[5],
                         (const float*)d_in[7], (const float*)d_in[9]};

    const int H   = in_sizes[3];          // 246
    const int E   = in_sizes[1] / 2;      // 320000
    const int FIN = in_sizes[2] / H;      // 256
    const int N   = in_sizes[0] / FIN;    // 50000

    auto align = [](size_t v) { return (v + 255) / 256 * 256; };
    char* ws = (char*)d_ws;
    size_t off = 0;
    int* flag = (int*)(ws + off);             off += 256;
    float* dinv = (float*)(ws + off);         off += align((size_t)N * 4);
    int* counts = (int*)(ws + off);           off += align((size_t)N * 4);
    int* starts = (int*)(ws + off);           off += align((size_t)(N + 1) * 4);
    int* srcs = (int*)(ws + off);             off += align((size_t)E * 4);
    unsigned short* Wh[4];
    unsigned short* Wl[4];
    for (int l = 0; l < 4; l++) {
        Wh[l] = (unsigned short*)(ws + off);  off += 256 * 256 * 2;
        Wl[l] = (unsigned short*)(ws + off);  off += 256 * 256 * 2;
    }
    // ping-pong hi/lo activation pairs; P0 also aliased as the final fp32 buf
    size_t pairB = align((size_t)N * 256 * 2);
    char* P0 = ws + off;                      off += 2 * pairB;
    char* P1 = ws + off;                      off += 2 * pairB;
    float* bufC = (float*)(ws + off);         off += align((size_t)N * H * 4);

    unsigned short* A0h = (unsigned short*)P0;
    unsigned short* A0l = (unsigned short*)(P0 + pairB);
    unsigned short* A1h = (unsigned short*)P1;
    unsigned short* A1l = (unsigned short*)(P1 + pairB);
    float* bufF = (float*)P0;                 // N*H*4 <= 2*pairB

    int nb = (N + 255) / 256, eb = (E + 255) / 256;

    // --- edge dtype detection ---
    k_flag_init<<<1, 64, 0, stream>>>(flag);
    k_flag_check<<<512, 256, 0, stream>>>((const long long*)eidx, E, (long long)N, flag);

    // --- CSR build ---
    k_zero_i32<<<nb, 256, 0, stream>>>(counts, N);
    k_count<<<eb, 256, 0, stream>>>(eidx, flag, counts, E);
    k_dinv<<<nb, 256, 0, stream>>>(counts, dinv, N);
    k_scan<<<1, 1024, 0, stream>>>(counts, starts, N);
    k_copy_i32<<<nb, 256, 0, stream>>>(starts, counts, N);
    k_fill<<<eb, 256, 0, stream>>>(eidx, flag, counts, srcs, E);

    // --- weight + input conversion ---
    k_cvt_w<<<256, 256, 0, stream>>>(W[0], Wh[0], Wl[0], FIN, H);
    for (int l = 1; l < 4; l++)
        k_cvt_w<<<256, 256, 0, stream>>>(W[l], Wh[l], Wl[l], H, H);
    k_cvt_x<<<2048, 256, 0, stream>>>(x, A0h, A0l, (long long)N * FIN);

    dim3 ggrid((256 + 127) / 128, (N + 127) / 128);   // 2 x 391

    // --- layer 1 ---
    k_gemm_mfma<<<ggrid, 256, 0, stream>>>(A0h, A0l, Wh[0], Wl[0], bufC, N, H);
    k_gather<<<N, 256, 0, stream>>>(bufC, srcs, starts, dinv, b[0], A1h, A1l,
                                    nullptr, H, 1);
    // --- layer 2 ---
    k_gemm_mfma<<<ggrid, 256, 0, stream>>>(A1h, A1l, Wh[1], Wl[1], bufC, N, H);
    k_gather<<<N, 256, 0, stream>>>(bufC, srcs, starts, dinv, b[1], A0h, A0l,
                                    nullptr, H, 1);
    // --- layer 3 ---
    k_gemm_mfma<<<ggrid, 256, 0, stream>>>(A0h, A0l, Wh[2], Wl[2], bufC, N, H);
    k_gather<<<N, 256, 0, stream>>>(bufC, srcs, starts, dinv, b[2], A1h, A1l,
                                    nullptr, H, 1);
    // --- layer 4 (no relu) + log_softmax ---
    k_gemm_mfma<<<ggrid, 256, 0, stream>>>(A1h, A1l, Wh[3], Wl[3], bufC, N, H);
    k_gather<<<N, 256, 0, stream>>>(bufC, srcs, starts, dinv, b[3], nullptr, nullptr,
                                    bufF, H, 0);
    k_logsoftmax<<<N, 256, 0, stream>>>(bufF, (float*)d_out, H);
}

// Round 4
// 579.147 us; speedup vs baseline: 3.6649x; 1.3082x over previous
//
#include <hip/hip_runtime.h>
#include <cstdint>
#include <cstddef>

// ---------------------------------------------------------------------------
// 4-layer GCN. Round 4: bf16 gather input (layers 1-3), wave-per-dst gather
// with shfl-broadcast edge lists, log_softmax fused into layer-4 gather.
// GEMM: split-bf16 (hi+lo) 3-pass MFMA, 128x128 tile (unchanged core).
// ---------------------------------------------------------------------------

typedef __bf16 bf16x8 __attribute__((ext_vector_type(8)));
typedef float f32x4 __attribute__((ext_vector_type(4)));

__device__ __forceinline__ unsigned short f2bf(float v) {   // RNE
    union { float f; unsigned u; } x; x.f = v;
    unsigned r = x.u + 0x7fff + ((x.u >> 16) & 1);
    return (unsigned short)(r >> 16);
}
__device__ __forceinline__ float bf2f(unsigned short h) {
    union { unsigned u; float f; } x; x.u = (unsigned)h << 16; return x.f;
}

// ---------------- edge-index dtype detection -------------------------------
__global__ void k_flag_init(int* flag) {
    if (blockIdx.x == 0 && threadIdx.x == 0) *flag = 1;
}

__global__ void k_flag_check(const long long* __restrict__ p, int E, long long N,
                             int* flag) {
    long long i = (long long)blockIdx.x * blockDim.x + threadIdx.x;
    long long stride = (long long)gridDim.x * blockDim.x;
    for (; i < E; i += stride) {
        long long v = p[i];
        if (v < 0 || v >= N) *flag = 0;
    }
}

__device__ __forceinline__ void load_edge(const void* eidx, int fl, int E, int i,
                                          int& s, int& d) {
    if (fl) {
        s = (int)((const long long*)eidx)[i];
        d = (int)((const long long*)eidx)[E + i];
    } else {
        s = ((const int*)eidx)[i];
        d = ((const int*)eidx)[E + i];
    }
}

// ---------------- CSR build -------------------------------------------------
__global__ void k_zero_i32(int* __restrict__ p, int n) {
    int i = blockIdx.x * blockDim.x + threadIdx.x;
    if (i < n) p[i] = 0;
}

__global__ void k_count(const void* __restrict__ eidx, const int* __restrict__ flag,
                        int* __restrict__ counts, int E) {
    int i = blockIdx.x * blockDim.x + threadIdx.x;
    if (i >= E) return;
    int s, d;
    load_edge(eidx, *flag, E, i, s, d);
    atomicAdd(&counts[d], 1);
}

__global__ void k_dinv(const int* __restrict__ counts, float* __restrict__ dinv,
                       int N) {
    int i = blockIdx.x * blockDim.x + threadIdx.x;
    if (i < N) dinv[i] = rsqrtf((float)counts[i] + 1.0f);
}

__global__ __launch_bounds__(1024) void k_scan(const int* __restrict__ counts,
                                               int* __restrict__ starts, int N) {
    __shared__ int wsum[16];
    __shared__ int wscan[16];
    __shared__ int s_carry;
    int tid = threadIdx.x;
    int lane = tid & 63, wid = tid >> 6;
    if (tid == 0) s_carry = 0;
    __syncthreads();
    for (int base = 0; base < N; base += 1024) {
        int i = base + tid;
        int v = (i < N) ? counts[i] : 0;
        int incl = v;
#pragma unroll
        for (int off = 1; off < 64; off <<= 1) {
            int t = __shfl_up(incl, off);
            if (lane >= off) incl += t;
        }
        if (lane == 63) wsum[wid] = incl;
        __syncthreads();
        if (wid == 0 && lane < 16) {
            int w = wsum[lane];
#pragma unroll
            for (int off = 1; off < 16; off <<= 1) {
                int t = __shfl_up(w, off);
                if (lane >= off) w += t;
            }
            wscan[lane] = w;
        }
        __syncthreads();
        int woff = (wid > 0) ? wscan[wid - 1] : 0;
        int excl = s_carry + woff + incl - v;
        if (i < N) starts[i] = excl;
        int total = wscan[15];
        __syncthreads();
        if (tid == 0) s_carry += total;
        __syncthreads();
    }
    if (tid == 0) starts[N] = s_carry;
}

__global__ void k_copy_i32(const int* __restrict__ a, int* __restrict__ b, int n) {
    int i = blockIdx.x * blockDim.x + threadIdx.x;
    if (i < n) b[i] = a[i];
}

__global__ void k_fill(const void* __restrict__ eidx, const int* __restrict__ flag,
                       int* __restrict__ cursor, int* __restrict__ srcs, int E) {
    int i = blockIdx.x * blockDim.x + threadIdx.x;
    if (i >= E) return;
    int s, d;
    load_edge(eidx, *flag, E, i, s, d);
    int pos = atomicAdd(&cursor[d], 1);
    srcs[pos] = s;
}

// ---------------- fp32 -> bf16 hi/lo conversions ---------------------------
__global__ void k_cvt_x(const float* __restrict__ x, unsigned short* __restrict__ hi,
                        unsigned short* __restrict__ lo, long long n) {
    long long i = (long long)blockIdx.x * blockDim.x + threadIdx.x;
    long long stride = (long long)gridDim.x * blockDim.x;
    for (; i < n; i += stride) {
        float v = x[i];
        unsigned short h = f2bf(v);
        hi[i] = h;
        lo[i] = f2bf(v - bf2f(h));
    }
}

// W [K][H] fp32 -> transposed, padded [256][256] bf16 hi/lo (zeros outside)
__global__ void k_cvt_w(const float* __restrict__ W, unsigned short* __restrict__ Thi,
                        unsigned short* __restrict__ Tlo, int K, int H) {
    int idx = blockIdx.x * blockDim.x + threadIdx.x;
    if (idx >= 256 * 256) return;
    int k = idx & 255, n = idx >> 8;
    float v = (k < K && n < H) ? W[k * H + n] : 0.0f;
    unsigned short h = f2bf(v);
    Thi[n * 256 + k] = h;
    Tlo[n * 256 + k] = f2bf(v - bf2f(h));
}

// ---------------- split-bf16 MFMA GEMM -------------------------------------
// C = A[M][256] @ W[256][H]; A hi/lo bf16, W transposed hi/lo [256][256].
// 128x128 tile, 4 waves, 4x4 grid of 16x16x32 MFMA, 3 passes (hh, lh, hl).
// mode 1: write bf16 Cb[M][256]; mode 0: write fp32 Cf[M][256].
__global__ __launch_bounds__(256) void k_gemm_mfma(
        const unsigned short* __restrict__ Ahi, const unsigned short* __restrict__ Alo,
        const unsigned short* __restrict__ BThi, const unsigned short* __restrict__ BTlo,
        unsigned short* __restrict__ Cb, float* __restrict__ Cf,
        int M, int H, int mode) {
    __shared__ unsigned short ldsA[2 * 4 * 128 * 8];
    __shared__ unsigned short ldsB[2 * 4 * 128 * 8];

    int tid = threadIdx.x;
    int lane = tid & 63;
    int w = tid >> 6;
    int wm = (w & 1) * 64, wn = (w >> 1) * 64;
    int kq = lane >> 4, lr = lane & 15;
    int row0 = blockIdx.y * 128, col0 = blockIdx.x * 128;

    f32x4 acc[4][4] = {};

    for (int k0 = 0; k0 < 256; k0 += 32) {
        __syncthreads();
#pragma unroll
        for (int i = 0; i < 4; i++) {
            int idx = tid + i * 256;
            int hl = idx >> 9;
            int rem = idx & 511;
            int kqq = rem & 3;
            int m = rem >> 2;
            int row = row0 + m;
            uint4 v = {0, 0, 0, 0};
            if (row < M) {
                const unsigned short* src = (hl ? Alo : Ahi) + (((long long)row) << 8)
                                            + k0 + kqq * 8;
                v = *(const uint4*)src;
            }
            *(uint4*)&ldsA[((hl * 4 + kqq) * 128 + m) * 8] = v;
        }
#pragma unroll
        for (int i = 0; i < 4; i++) {
            int idx = tid + i * 256;
            int hl = idx >> 9;
            int rem = idx & 511;
            int kqq = rem & 3;
            int n = rem >> 2;
            const unsigned short* src = (hl ? BTlo : BThi)
                                        + (((long long)(col0 + n)) << 8) + k0 + kqq * 8;
            *(uint4*)&ldsB[((hl * 4 + kqq) * 128 + n) * 8] = *(const uint4*)src;
        }
        __syncthreads();

        bf16x8 ah[4], al[4], bh[4], bl[4];
#pragma unroll
        for (int t = 0; t < 4; t++) {
            int m = wm + t * 16 + lr;
            ah[t] = *(const bf16x8*)&ldsA[((0 * 4 + kq) * 128 + m) * 8];
            al[t] = *(const bf16x8*)&ldsA[((1 * 4 + kq) * 128 + m) * 8];
            int n = wn + t * 16 + lr;
            bh[t] = *(const bf16x8*)&ldsB[((0 * 4 + kq) * 128 + n) * 8];
            bl[t] = *(const bf16x8*)&ldsB[((1 * 4 + kq) * 128 + n) * 8];
        }
#pragma unroll
        for (int mt = 0; mt < 4; mt++)
#pragma unroll
            for (int nt = 0; nt < 4; nt++) {
                acc[mt][nt] = __builtin_amdgcn_mfma_f32_16x16x32_bf16(
                    ah[mt], bh[nt], acc[mt][nt], 0, 0, 0);
                acc[mt][nt] = __builtin_amdgcn_mfma_f32_16x16x32_bf16(
                    al[mt], bh[nt], acc[mt][nt], 0, 0, 0);
                acc[mt][nt] = __builtin_amdgcn_mfma_f32_16x16x32_bf16(
                    ah[mt], bl[nt], acc[mt][nt], 0, 0, 0);
            }
    }

    // epilogue: C/D layout col=lane&15, row=(lane>>4)*4+reg  [m89-verified]
#pragma unroll
    for (int mt = 0; mt < 4; mt++) {
#pragma unroll
        for (int nt = 0; nt < 4; nt++) {
            int col = col0 + wn + nt * 16 + lr;
            int rowb = row0 + wm + mt * 16 + kq * 4;
            if (col < H) {
#pragma unroll
                for (int r = 0; r < 4; r++) {
                    int row = rowb + r;
                    if (row < M) {
                        if (mode) Cb[(long long)row * 256 + col] = f2bf(acc[mt][nt][r]);
                        else      Cf[(long long)row * 256 + col] = acc[mt][nt][r];
                    }
                }
            }
        }
    }
}

// ---------------- wave-per-dst CSR gather (bf16 input, hi/lo output) -------
// out = relu( dinv[d]*( h[d]*dinv[d] + sum_s h[s]*dinv[s] ) + bias )
__global__ __launch_bounds__(256) void k_gather_bf16(
        const unsigned short* __restrict__ h,   // bf16 [N][256]
        const int* __restrict__ srcs, const int* __restrict__ starts,
        const float* __restrict__ dinv, const float* __restrict__ bias,
        unsigned short* __restrict__ out_hi, unsigned short* __restrict__ out_lo,
        int N, int H) {
    int d = blockIdx.x * 4 + (threadIdx.x >> 6);
    if (d >= N) return;
    int lane = threadIdx.x & 63;
    int f0 = lane * 4;
    float dd = dinv[d];
    int e0 = starts[d], e1 = starts[d + 1];
    int cnt = e1 - e0;
    int cpre = cnt < 64 ? cnt : 64;

    float acc[4];
    {   // self-loop
        uint2 v = *(const uint2*)&h[((long long)d << 8) + f0];
        acc[0] = bf2f((unsigned short)(v.x & 0xffff)) * dd;
        acc[1] = bf2f((unsigned short)(v.x >> 16)) * dd;
        acc[2] = bf2f((unsigned short)(v.y & 0xffff)) * dd;
        acc[3] = bf2f((unsigned short)(v.y >> 16)) * dd;
    }
    // coalesced edge preload + shfl broadcast
    int sv = 0; float nv = 0.0f;
    if (lane < cpre) { sv = srcs[e0 + lane]; nv = dinv[sv]; }
    int j = 0;
    for (; j + 1 < cpre; j += 2) {
        int s0 = __shfl(sv, j), s1 = __shfl(sv, j + 1);
        float n0 = __shfl(nv, j), n1 = __shfl(nv, j + 1);
        uint2 v0 = *(const uint2*)&h[((long long)s0 << 8) + f0];
        uint2 v1 = *(const uint2*)&h[((long long)s1 << 8) + f0];
        acc[0] += bf2f((unsigned short)(v0.x & 0xffff)) * n0
                + bf2f((unsigned short)(v1.x & 0xffff)) * n1;
        acc[1] += bf2f((unsigned short)(v0.x >> 16)) * n0
                + bf2f((unsigned short)(v1.x >> 16)) * n1;
        acc[2] += bf2f((unsigned short)(v0.y & 0xffff)) * n0
                + bf2f((unsigned short)(v1.y & 0xffff)) * n1;
        acc[3] += bf2f((unsigned short)(v0.y >> 16)) * n0
                + bf2f((unsigned short)(v1.y >> 16)) * n1;
    }
    if (j < cpre) {
        int s0 = __shfl(sv, j);
        float n0 = __shfl(nv, j);
        uint2 v0 = *(const uint2*)&h[((long long)s0 << 8) + f0];
        acc[0] += bf2f((unsigned short)(v0.x & 0xffff)) * n0;
        acc[1] += bf2f((unsigned short)(v0.x >> 16)) * n0;
        acc[2] += bf2f((unsigned short)(v0.y & 0xffff)) * n0;
        acc[3] += bf2f((unsigned short)(v0.y >> 16)) * n0;
    }
    for (int e = e0 + 64; e < e1; e++) {          // rare: degree > 64
        int s0 = srcs[e];
        float n0 = dinv[s0];
        uint2 v0 = *(const uint2*)&h[((long long)s0 << 8) + f0];
        acc[0] += bf2f((unsigned short)(v0.x & 0xffff)) * n0;
        acc[1] += bf2f((unsigned short)(v0.x >> 16)) * n0;
        acc[2] += bf2f((unsigned short)(v0.y & 0xffff)) * n0;
        acc[3] += bf2f((unsigned short)(v0.y >> 16)) * n0;
    }

    unsigned hi01, hi23, lo01, lo23;
    unsigned short hi[4], lo[4];
#pragma unroll
    for (int t = 0; t < 4; t++) {
        int f = f0 + t;
        float bb = (f < H) ? bias[f] : 0.0f;
        float v = fmaxf(acc[t] * dd + bb, 0.0f);   // relu (layers 1-3 only)
        hi[t] = f2bf(v);
        lo[t] = f2bf(v - bf2f(hi[t]));
    }
    hi01 = (unsigned)hi[0] | ((unsigned)hi[1] << 16);
    hi23 = (unsigned)hi[2] | ((unsigned)hi[3] << 16);
    lo01 = (unsigned)lo[0] | ((unsigned)lo[1] << 16);
    lo23 = (unsigned)lo[2] | ((unsigned)lo[3] << 16);
    *(uint2*)&out_hi[((long long)d << 8) + f0] = make_uint2(hi01, hi23);
    *(uint2*)&out_lo[((long long)d << 8) + f0] = make_uint2(lo01, lo23);
}

// ---------------- layer-4: fp32 gather + fused log_softmax -----------------
__global__ __launch_bounds__(256) void k_gather_lsm(
        const float* __restrict__ h,            // fp32 [N][256]
        const int* __restrict__ srcs, const int* __restrict__ starts,
        const float* __restrict__ dinv, const float* __restrict__ bias,
        float* __restrict__ out, int N, int H) {
    int d = blockIdx.x * 4 + (threadIdx.x >> 6);
    if (d >= N) return;
    int lane = threadIdx.x & 63;
    int f0 = lane * 4;
    float dd = dinv[d];
    int e0 = starts[d], e1 = starts[d + 1];
    int cnt = e1 - e0;
    int cpre = cnt < 64 ? cnt : 64;

    float4 sv4 = *(const float4*)&h[((long long)d << 8) + f0];
    float acc[4] = {sv4.x * dd, sv4.y * dd, sv4.z * dd, sv4.w * dd};

    int sv = 0; float nv = 0.0f;
    if (lane < cpre) { sv = srcs[e0 + lane]; nv = dinv[sv]; }
    int j = 0;
    for (; j + 1 < cpre; j += 2) {
        int s0 = __shfl(sv, j), s1 = __shfl(sv, j + 1);
        float n0 = __shfl(nv, j), n1 = __shfl(nv, j + 1);
        float4 v0 = *(const float4*)&h[((long long)s0 << 8) + f0];
        float4 v1 = *(const float4*)&h[((long long)s1 << 8) + f0];
        acc[0] += v0.x * n0 + v1.x * n1;
        acc[1] += v0.y * n0 + v1.y * n1;
        acc[2] += v0.z * n0 + v1.z * n1;
        acc[3] += v0.w * n0 + v1.w * n1;
    }
    if (j < cpre) {
        int s0 = __shfl(sv, j);
        float n0 = __shfl(nv, j);
        float4 v0 = *(const float4*)&h[((long long)s0 << 8) + f0];
        acc[0] += v0.x * n0; acc[1] += v0.y * n0;
        acc[2] += v0.z * n0; acc[3] += v0.w * n0;
    }
    for (int e = e0 + 64; e < e1; e++) {
        int s0 = srcs[e];
        float n0 = dinv[s0];
        float4 v0 = *(const float4*)&h[((long long)s0 << 8) + f0];
        acc[0] += v0.x * n0; acc[1] += v0.y * n0;
        acc[2] += v0.z * n0; acc[3] += v0.w * n0;
    }

    float v[4];
    float m = -INFINITY;
#pragma unroll
    for (int t = 0; t < 4; t++) {
        int f = f0 + t;
        float bb = (f < H) ? bias[f] : 0.0f;
        v[t] = acc[t] * dd + bb;
        if (f < H) m = fmaxf(m, v[t]);
    }
#pragma unroll
    for (int off = 32; off > 0; off >>= 1) m = fmaxf(m, __shfl_xor(m, off));
    float s = 0.0f;
#pragma unroll
    for (int t = 0; t < 4; t++) {
        int f = f0 + t;
        if (f < H) s += __expf(v[t] - m);
    }
#pragma unroll
    for (int off = 32; off > 0; off >>= 1) s += __shfl_xor(s, off);
    float lse = m + logf(s);
#pragma unroll
    for (int t = 0; t < 4; t++) {
        int f = f0 + t;
        if (f < H) out[(long long)d * H + f] = v[t] - lse;
    }
}

// ---------------------------------------------------------------------------
extern "C" void kernel_launch(void* const* d_in, const int* in_sizes, int n_in,
                              void* d_out, int out_size, void* d_ws, size_t ws_size,
                              hipStream_t stream) {
    const float* x    = (const float*)d_in[0];
    const void*  eidx = d_in[1];
    const float* W[4] = {(const float*)d_in[2], (const float*)d_in[4],
                         (const float*)d_in[6], (const float*)d_in[8]};
    const float* b[4] = {(const float*)d_in[3], (const float*)d_in[5],
                         (const float*)d_in[7], (const float*)d_in[9]};

    const int H   = in_sizes[3];          // 246
    const int E   = in_sizes[1] / 2;      // 320000
    const int FIN = in_sizes[2] / H;      // 256
    const int N   = in_sizes[0] / FIN;    // 50000

    auto align = [](size_t v) { return (v + 255) / 256 * 256; };
    char* ws = (char*)d_ws;
    size_t off = 0;
    int* flag = (int*)(ws + off);             off += 256;
    float* dinv = (float*)(ws + off);         off += align((size_t)N * 4);
    int* counts = (int*)(ws + off);           off += align((size_t)N * 4);
    int* starts = (int*)(ws + off);           off += align((size_t)(N + 1) * 4);
    int* srcs = (int*)(ws + off);             off += align((size_t)E * 4);
    unsigned short* Wh[4];
    unsigned short* Wl[4];
    for (int l = 0; l < 4; l++) {
        Wh[l] = (unsigned short*)(ws + off);  off += 256 * 256 * 2;
        Wl[l] = (unsigned short*)(ws + off);  off += 256 * 256 * 2;
    }
    size_t pairB = align((size_t)N * 256 * 2);
    char* P0 = ws + off;                      off += 2 * pairB;
    char* P1 = ws + off;                      off += 2 * pairB;
    // bufC: shared region, bf16 [N][256] (layers 1-3) or fp32 [N][256] (layer 4)
    char* CR = ws + off;                      off += align((size_t)N * 256 * 4);
    unsigned short* bufCb = (unsigned short*)CR;
    float* bufCf = (float*)CR;

    unsigned short* A0h = (unsigned short*)P0;
    unsigned short* A0l = (unsigned short*)(P0 + pairB);
    unsigned short* A1h = (unsigned short*)P1;
    unsigned short* A1l = (unsigned short*)(P1 + pairB);

    int nb = (N + 255) / 256, eb = (E + 255) / 256;

    // --- edge dtype detection ---
    k_flag_init<<<1, 64, 0, stream>>>(flag);
    k_flag_check<<<512, 256, 0, stream>>>((const long long*)eidx, E, (long long)N, flag);

    // --- CSR build ---
    k_zero_i32<<<nb, 256, 0, stream>>>(counts, N);
    k_count<<<eb, 256, 0, stream>>>(eidx, flag, counts, E);
    k_dinv<<<nb, 256, 0, stream>>>(counts, dinv, N);
    k_scan<<<1, 1024, 0, stream>>>(counts, starts, N);
    k_copy_i32<<<nb, 256, 0, stream>>>(starts, counts, N);
    k_fill<<<eb, 256, 0, stream>>>(eidx, flag, counts, srcs, E);

    // --- weight + input conversion ---
    k_cvt_w<<<256, 256, 0, stream>>>(W[0], Wh[0], Wl[0], FIN, H);
    for (int l = 1; l < 4; l++)
        k_cvt_w<<<256, 256, 0, stream>>>(W[l], Wh[l], Wl[l], H, H);
    k_cvt_x<<<2048, 256, 0, stream>>>(x, A0h, A0l, (long long)N * FIN);

    dim3 ggrid(2, (N + 127) / 128);
    int gb = (N + 3) / 4;                      // wave-per-dst gather blocks

    // --- layer 1 ---
    k_gemm_mfma<<<ggrid, 256, 0, stream>>>(A0h, A0l, Wh[0], Wl[0], bufCb, nullptr,
                                           N, H, 1);
    k_gather_bf16<<<gb, 256, 0, stream>>>(bufCb, srcs, starts, dinv, b[0], A1h, A1l,
                                          N, H);
    // --- layer 2 ---
    k_gemm_mfma<<<ggrid, 256, 0, stream>>>(A1h, A1l, Wh[1], Wl[1], bufCb, nullptr,
                                           N, H, 1);
    k_gather_bf16<<<gb, 256, 0, stream>>>(bufCb, srcs, starts, dinv, b[1], A0h, A0l,
                                          N, H);
    // --- layer 3 ---
    k_gemm_mfma<<<ggrid, 256, 0, stream>>>(A0h, A0l, Wh[2], Wl[2], bufCb, nullptr,
                                           N, H, 1);
    k_gather_bf16<<<gb, 256, 0, stream>>>(bufCb, srcs, starts, dinv, b[2], A1h, A1l,
                                          N, H);
    // --- layer 4 (fp32 C, fused log_softmax) ---
    k_gemm_mfma<<<ggrid, 256, 0, stream>>>(A1h, A1l, Wh[3], Wl[3], nullptr, bufCf,
                                           N, H, 0);
    k_gather_lsm<<<gb, 256, 0, stream>>>(bufCf, srcs, starts, dinv, b[3],
                                         (float*)d_out, N, H);
}

// Round 5
// 496.054 us; speedup vs baseline: 4.2788x; 1.1675x over previous
//
#include <hip/hip_runtime.h>
#include <cstdint>
#include <cstddef>

// ---------------------------------------------------------------------------
// 4-layer GCN. Round 5: plain-bf16 activations (W stays split hi/lo, 2-pass
// MFMA), global_load_lds width-16 staging in the GEMM, all gathers bf16.
// ---------------------------------------------------------------------------

typedef __bf16 bf16x8 __attribute__((ext_vector_type(8)));
typedef float f32x4 __attribute__((ext_vector_type(4)));

__device__ __forceinline__ unsigned short f2bf(float v) {   // RNE
    union { float f; unsigned u; } x; x.f = v;
    unsigned r = x.u + 0x7fff + ((x.u >> 16) & 1);
    return (unsigned short)(r >> 16);
}
__device__ __forceinline__ float bf2f(unsigned short h) {
    union { unsigned u; float f; } x; x.u = (unsigned)h << 16; return x.f;
}

// async global->LDS, 16B per lane; lds base must be wave-uniform
__device__ __forceinline__ void gl2lds16(const void* g, void* l) {
    __builtin_amdgcn_global_load_lds(
        (const __attribute__((address_space(1))) unsigned int*)g,
        (__attribute__((address_space(3))) unsigned int*)l, 16, 0, 0);
}

// ---------------- edge-index dtype detection -------------------------------
__global__ void k_flag_init(int* flag) {
    if (blockIdx.x == 0 && threadIdx.x == 0) *flag = 1;
}

__global__ void k_flag_check(const long long* __restrict__ p, int E, long long N,
                             int* flag) {
    long long i = (long long)blockIdx.x * blockDim.x + threadIdx.x;
    long long stride = (long long)gridDim.x * blockDim.x;
    for (; i < E; i += stride) {
        long long v = p[i];
        if (v < 0 || v >= N) *flag = 0;
    }
}

__device__ __forceinline__ void load_edge(const void* eidx, int fl, int E, int i,
                                          int& s, int& d) {
    if (fl) {
        s = (int)((const long long*)eidx)[i];
        d = (int)((const long long*)eidx)[E + i];
    } else {
        s = ((const int*)eidx)[i];
        d = ((const int*)eidx)[E + i];
    }
}

// ---------------- CSR build -------------------------------------------------
__global__ void k_zero_i32(int* __restrict__ p, int n) {
    int i = blockIdx.x * blockDim.x + threadIdx.x;
    if (i < n) p[i] = 0;
}

__global__ void k_count(const void* __restrict__ eidx, const int* __restrict__ flag,
                        int* __restrict__ counts, int E) {
    int i = blockIdx.x * blockDim.x + threadIdx.x;
    if (i >= E) return;
    int s, d;
    load_edge(eidx, *flag, E, i, s, d);
    atomicAdd(&counts[d], 1);
}

__global__ void k_dinv(const int* __restrict__ counts, float* __restrict__ dinv,
                       int N) {
    int i = blockIdx.x * blockDim.x + threadIdx.x;
    if (i < N) dinv[i] = rsqrtf((float)counts[i] + 1.0f);
}

__global__ __launch_bounds__(1024) void k_scan(const int* __restrict__ counts,
                                               int* __restrict__ starts, int N) {
    __shared__ int wsum[16];
    __shared__ int wscan[16];
    __shared__ int s_carry;
    int tid = threadIdx.x;
    int lane = tid & 63, wid = tid >> 6;
    if (tid == 0) s_carry = 0;
    __syncthreads();
    for (int base = 0; base < N; base += 1024) {
        int i = base + tid;
        int v = (i < N) ? counts[i] : 0;
        int incl = v;
#pragma unroll
        for (int off = 1; off < 64; off <<= 1) {
            int t = __shfl_up(incl, off);
            if (lane >= off) incl += t;
        }
        if (lane == 63) wsum[wid] = incl;
        __syncthreads();
        if (wid == 0 && lane < 16) {
            int w = wsum[lane];
#pragma unroll
            for (int off = 1; off < 16; off <<= 1) {
                int t = __shfl_up(w, off);
                if (lane >= off) w += t;
            }
            wscan[lane] = w;
        }
        __syncthreads();
        int woff = (wid > 0) ? wscan[wid - 1] : 0;
        int excl = s_carry + woff + incl - v;
        if (i < N) starts[i] = excl;
        int total = wscan[15];
        __syncthreads();
        if (tid == 0) s_carry += total;
        __syncthreads();
    }
    if (tid == 0) starts[N] = s_carry;
}

__global__ void k_copy_i32(const int* __restrict__ a, int* __restrict__ b, int n) {
    int i = blockIdx.x * blockDim.x + threadIdx.x;
    if (i < n) b[i] = a[i];
}

__global__ void k_fill(const void* __restrict__ eidx, const int* __restrict__ flag,
                       int* __restrict__ cursor, int* __restrict__ srcs, int E) {
    int i = blockIdx.x * blockDim.x + threadIdx.x;
    if (i >= E) return;
    int s, d;
    load_edge(eidx, *flag, E, i, s, d);
    int pos = atomicAdd(&cursor[d], 1);
    srcs[pos] = s;
}

// ---------------- conversions ----------------------------------------------
// x fp32 -> plain bf16, vectorized x4
__global__ void k_cvt_x(const float* __restrict__ x, unsigned short* __restrict__ o,
                        long long n4) {
    long long i = (long long)blockIdx.x * blockDim.x + threadIdx.x;
    long long stride = (long long)gridDim.x * blockDim.x;
    for (; i < n4; i += stride) {
        float4 v = ((const float4*)x)[i];
        unsigned a = (unsigned)f2bf(v.x) | ((unsigned)f2bf(v.y) << 16);
        unsigned b = (unsigned)f2bf(v.z) | ((unsigned)f2bf(v.w) << 16);
        ((uint2*)o)[i] = make_uint2(a, b);
    }
}

// W [K][H] fp32 -> transposed, padded [256][256] bf16 hi/lo (zeros outside)
__global__ void k_cvt_w(const float* __restrict__ W, unsigned short* __restrict__ Thi,
                        unsigned short* __restrict__ Tlo, int K, int H) {
    int idx = blockIdx.x * blockDim.x + threadIdx.x;
    if (idx >= 256 * 256) return;
    int k = idx & 255, n = idx >> 8;
    float v = (k < K && n < H) ? W[k * H + n] : 0.0f;
    unsigned short h = f2bf(v);
    Thi[n * 256 + k] = h;
    Tlo[n * 256 + k] = f2bf(v - bf2f(h));
}

// ---------------- 2-pass split-W bf16 MFMA GEMM ----------------------------
// C[M][256] = A[M][256] @ W[256][256]; A plain bf16, W transposed hi/lo.
// 128x128 tile, 4 waves, 4x4 grid of 16x16x32 MFMA, passes (a*bh + a*bl).
// Staging via global_load_lds (16B/lane, wave-uniform LDS base).
__global__ __launch_bounds__(256) void k_gemm_mfma(
        const unsigned short* __restrict__ A,
        const unsigned short* __restrict__ BThi, const unsigned short* __restrict__ BTlo,
        unsigned short* __restrict__ C, int M) {
    __shared__ unsigned short ldsA[4 * 128 * 8];        // chunk c = kq*128+m
    __shared__ unsigned short ldsB[2 * 4 * 128 * 8];    // chunk c = hl*512+kq*128+n

    int tid = threadIdx.x;
    int lane = tid & 63;
    int w = tid >> 6;
    int wm = (w & 1) * 64, wn = (w >> 1) * 64;
    int kq = lane >> 4, lr = lane & 15;
    int row0 = blockIdx.y * 128, col0 = blockIdx.x * 128;

    f32x4 acc[4][4] = {};

    for (int k0 = 0; k0 < 256; k0 += 32) {
        __syncthreads();      // previous iter's ds_reads done before overwrite
        // A: 512 chunks of 16B; wave w issues 2 loads, 64 consecutive chunks each
#pragma unroll
        for (int i = 0; i < 2; i++) {
            int c = (i * 4 + w) * 64 + lane;
            int m = c & 127, kqq = c >> 7;
            int row = row0 + m; if (row >= M) row = M - 1;   // clamp: valid addr
            gl2lds16(&A[(long long)row * 256 + k0 + kqq * 8],
                     &ldsA[(i * 4 + w) * 512]);
        }
        // B: 1024 chunks (hi then lo); wave w issues 4 loads
#pragma unroll
        for (int i = 0; i < 4; i++) {
            int c = (i * 4 + w) * 64 + lane;
            int n = c & 127, kqq = (c >> 7) & 3, hl = c >> 9;
            const unsigned short* src = (hl ? BTlo : BThi)
                                        + (long long)(col0 + n) * 256 + k0 + kqq * 8;
            gl2lds16(src, &ldsB[(i * 4 + w) * 512]);
        }
        __syncthreads();      // compiler drains vmcnt(0) before barrier

        bf16x8 a[4], bh[4], bl[4];
#pragma unroll
        for (int t = 0; t < 4; t++) {
            int m = wm + t * 16 + lr;
            a[t] = *(const bf16x8*)&ldsA[(kq * 128 + m) * 8];
            int n = wn + t * 16 + lr;
            bh[t] = *(const bf16x8*)&ldsB[(kq * 128 + n) * 8];
            bl[t] = *(const bf16x8*)&ldsB[(512 + kq * 128 + n) * 8];
        }
#pragma unroll
        for (int mt = 0; mt < 4; mt++)
#pragma unroll
            for (int nt = 0; nt < 4; nt++) {
                acc[mt][nt] = __builtin_amdgcn_mfma_f32_16x16x32_bf16(
                    a[mt], bh[nt], acc[mt][nt], 0, 0, 0);
                acc[mt][nt] = __builtin_amdgcn_mfma_f32_16x16x32_bf16(
                    a[mt], bl[nt], acc[mt][nt], 0, 0, 0);
            }
    }

    // epilogue: C/D layout col=lane&15, row=(lane>>4)*4+reg  [m89-verified]
    // write ALL 256 cols (pad cols compute to 0 via zero W cols -> keeps pad clean)
#pragma unroll
    for (int mt = 0; mt < 4; mt++) {
#pragma unroll
        for (int nt = 0; nt < 4; nt++) {
            int col = col0 + wn + nt * 16 + lr;
            int rowb = row0 + wm + mt * 16 + kq * 4;
#pragma unroll
            for (int r = 0; r < 4; r++) {
                int row = rowb + r;
                if (row < M) C[(long long)row * 256 + col] = f2bf(acc[mt][nt][r]);
            }
        }
    }
}

// ---------------- wave-per-dst CSR gather (bf16 in, bf16 out) --------------
// out = relu( dinv[d]*( h[d]*dinv[d] + sum_s h[s]*dinv[s] ) + bias )
__global__ __launch_bounds__(256) void k_gather_bf16(
        const unsigned short* __restrict__ h,   // bf16 [N][256]
        const int* __restrict__ srcs, const int* __restrict__ starts,
        const float* __restrict__ dinv, const float* __restrict__ bias,
        unsigned short* __restrict__ out, int N, int H) {
    int d = blockIdx.x * 4 + (threadIdx.x >> 6);
    if (d >= N) return;
    int lane = threadIdx.x & 63;
    int f0 = lane * 4;
    float dd = dinv[d];
    int e0 = starts[d], e1 = starts[d + 1];
    int cnt = e1 - e0;
    int cpre = cnt < 64 ? cnt : 64;

    float acc[4];
    {   // self-loop
        uint2 v = *(const uint2*)&h[((long long)d << 8) + f0];
        acc[0] = bf2f((unsigned short)(v.x & 0xffff)) * dd;
        acc[1] = bf2f((unsigned short)(v.x >> 16)) * dd;
        acc[2] = bf2f((unsigned short)(v.y & 0xffff)) * dd;
        acc[3] = bf2f((unsigned short)(v.y >> 16)) * dd;
    }
    int sv = 0; float nv = 0.0f;
    if (lane < cpre) { sv = srcs[e0 + lane]; nv = dinv[sv]; }
    int j = 0;
    for (; j + 1 < cpre; j += 2) {
        int s0 = __shfl(sv, j), s1 = __shfl(sv, j + 1);
        float n0 = __shfl(nv, j), n1 = __shfl(nv, j + 1);
        uint2 v0 = *(const uint2*)&h[((long long)s0 << 8) + f0];
        uint2 v1 = *(const uint2*)&h[((long long)s1 << 8) + f0];
        acc[0] += bf2f((unsigned short)(v0.x & 0xffff)) * n0
                + bf2f((unsigned short)(v1.x & 0xffff)) * n1;
        acc[1] += bf2f((unsigned short)(v0.x >> 16)) * n0
                + bf2f((unsigned short)(v1.x >> 16)) * n1;
        acc[2] += bf2f((unsigned short)(v0.y & 0xffff)) * n0
                + bf2f((unsigned short)(v1.y & 0xffff)) * n1;
        acc[3] += bf2f((unsigned short)(v0.y >> 16)) * n0
                + bf2f((unsigned short)(v1.y >> 16)) * n1;
    }
    if (j < cpre) {
        int s0 = __shfl(sv, j);
        float n0 = __shfl(nv, j);
        uint2 v0 = *(const uint2*)&h[((long long)s0 << 8) + f0];
        acc[0] += bf2f((unsigned short)(v0.x & 0xffff)) * n0;
        acc[1] += bf2f((unsigned short)(v0.x >> 16)) * n0;
        acc[2] += bf2f((unsigned short)(v0.y & 0xffff)) * n0;
        acc[3] += bf2f((unsigned short)(v0.y >> 16)) * n0;
    }
    for (int e = e0 + 64; e < e1; e++) {          // rare: degree > 64
        int s0 = srcs[e];
        float n0 = dinv[s0];
        uint2 v0 = *(const uint2*)&h[((long long)s0 << 8) + f0];
        acc[0] += bf2f((unsigned short)(v0.x & 0xffff)) * n0;
        acc[1] += bf2f((unsigned short)(v0.x >> 16)) * n0;
        acc[2] += bf2f((unsigned short)(v0.y & 0xffff)) * n0;
        acc[3] += bf2f((unsigned short)(v0.y >> 16)) * n0;
    }

    unsigned short o[4];
#pragma unroll
    for (int t = 0; t < 4; t++) {
        int f = f0 + t;
        float bb = (f < H) ? bias[f] : 0.0f;
        float v = fmaxf(acc[t] * dd + bb, 0.0f);   // relu
        o[t] = f2bf(v);
    }
    unsigned o01 = (unsigned)o[0] | ((unsigned)o[1] << 16);
    unsigned o23 = (unsigned)o[2] | ((unsigned)o[3] << 16);
    *(uint2*)&out[((long long)d << 8) + f0] = make_uint2(o01, o23);
}

// ---------------- layer-4: bf16 gather + fused log_softmax -----------------
__global__ __launch_bounds__(256) void k_gather_lsm(
        const unsigned short* __restrict__ h,   // bf16 [N][256]
        const int* __restrict__ srcs, const int* __restrict__ starts,
        const float* __restrict__ dinv, const float* __restrict__ bias,
        float* __restrict__ out, int N, int H) {
    int d = blockIdx.x * 4 + (threadIdx.x >> 6);
    if (d >= N) return;
    int lane = threadIdx.x & 63;
    int f0 = lane * 4;
    float dd = dinv[d];
    int e0 = starts[d], e1 = starts[d + 1];
    int cnt = e1 - e0;
    int cpre = cnt < 64 ? cnt : 64;

    float acc[4];
    {
        uint2 v = *(const uint2*)&h[((long long)d << 8) + f0];
        acc[0] = bf2f((unsigned short)(v.x & 0xffff)) * dd;
        acc[1] = bf2f((unsigned short)(v.x >> 16)) * dd;
        acc[2] = bf2f((unsigned short)(v.y & 0xffff)) * dd;
        acc[3] = bf2f((unsigned short)(v.y >> 16)) * dd;
    }
    int sv = 0; float nv = 0.0f;
    if (lane < cpre) { sv = srcs[e0 + lane]; nv = dinv[sv]; }
    int j = 0;
    for (; j + 1 < cpre; j += 2) {
        int s0 = __shfl(sv, j), s1 = __shfl(sv, j + 1);
        float n0 = __shfl(nv, j), n1 = __shfl(nv, j + 1);
        uint2 v0 = *(const uint2*)&h[((long long)s0 << 8) + f0];
        uint2 v1 = *(const uint2*)&h[((long long)s1 << 8) + f0];
        acc[0] += bf2f((unsigned short)(v0.x & 0xffff)) * n0
                + bf2f((unsigned short)(v1.x & 0xffff)) * n1;
        acc[1] += bf2f((unsigned short)(v0.x >> 16)) * n0
                + bf2f((unsigned short)(v1.x >> 16)) * n1;
        acc[2] += bf2f((unsigned short)(v0.y & 0xffff)) * n0
                + bf2f((unsigned short)(v1.y & 0xffff)) * n1;
        acc[3] += bf2f((unsigned short)(v0.y >> 16)) * n0
                + bf2f((unsigned short)(v1.y >> 16)) * n1;
    }
    if (j < cpre) {
        int s0 = __shfl(sv, j);
        float n0 = __shfl(nv, j);
        uint2 v0 = *(const uint2*)&h[((long long)s0 << 8) + f0];
        acc[0] += bf2f((unsigned short)(v0.x & 0xffff)) * n0;
        acc[1] += bf2f((unsigned short)(v0.x >> 16)) * n0;
        acc[2] += bf2f((unsigned short)(v0.y & 0xffff)) * n0;
        acc[3] += bf2f((unsigned short)(v0.y >> 16)) * n0;
    }
    for (int e = e0 + 64; e < e1; e++) {
        int s0 = srcs[e];
        float n0 = dinv[s0];
        uint2 v0 = *(const uint2*)&h[((long long)s0 << 8) + f0];
        acc[0] += bf2f((unsigned short)(v0.x & 0xffff)) * n0;
        acc[1] += bf2f((unsigned short)(v0.x >> 16)) * n0;
        acc[2] += bf2f((unsigned short)(v0.y & 0xffff)) * n0;
        acc[3] += bf2f((unsigned short)(v0.y >> 16)) * n0;
    }

    float v[4];
    float m = -INFINITY;
#pragma unroll
    for (int t = 0; t < 4; t++) {
        int f = f0 + t;
        float bb = (f < H) ? bias[f] : 0.0f;
        v[t] = acc[t] * dd + bb;
        if (f < H) m = fmaxf(m, v[t]);
    }
#pragma unroll
    for (int off = 32; off > 0; off >>= 1) m = fmaxf(m, __shfl_xor(m, off));
    float s = 0.0f;
#pragma unroll
    for (int t = 0; t < 4; t++) {
        int f = f0 + t;
        if (f < H) s += __expf(v[t] - m);
    }
#pragma unroll
    for (int off = 32; off > 0; off >>= 1) s += __shfl_xor(s, off);
    float lse = m + logf(s);
#pragma unroll
    for (int t = 0; t < 4; t++) {
        int f = f0 + t;
        if (f < H) out[(long long)d * H + f] = v[t] - lse;
    }
}

// ---------------------------------------------------------------------------
extern "C" void kernel_launch(void* const* d_in, const int* in_sizes, int n_in,
                              void* d_out, int out_size, void* d_ws, size_t ws_size,
                              hipStream_t stream) {
    const float* x    = (const float*)d_in[0];
    const void*  eidx = d_in[1];
    const float* W[4] = {(const float*)d_in[2], (const float*)d_in[4],
                         (const float*)d_in[6], (const float*)d_in[8]};
    const float* b[4] = {(const float*)d_in[3], (const float*)d_in[5],
                         (const float*)d_in[7], (const float*)d_in[9]};

    const int H   = in_sizes[3];          // 246
    const int E   = in_sizes[1] / 2;      // 320000
    const int FIN = in_sizes[2] / H;      // 256
    const int N   = in_sizes[0] / FIN;    // 50000

    auto align = [](size_t v) { return (v + 255) / 256 * 256; };
    char* ws = (char*)d_ws;
    size_t off = 0;
    int* flag = (int*)(ws + off);             off += 256;
    float* dinv = (float*)(ws + off);         off += align((size_t)N * 4);
    int* counts = (int*)(ws + off);           off += align((size_t)N * 4);
    int* starts = (int*)(ws + off);           off += align((size_t)(N + 1) * 4);
    int* srcs = (int*)(ws + off);             off += align((size_t)E * 4);
    unsigned short* Wh[4];
    unsigned short* Wl[4];
    for (int l = 0; l < 4; l++) {
        Wh[l] = (unsigned short*)(ws + off);  off += 256 * 256 * 2;
        Wl[l] = (unsigned short*)(ws + off);  off += 256 * 256 * 2;
    }
    size_t actB = align((size_t)N * 256 * 2);
    unsigned short* A0 = (unsigned short*)(ws + off);  off += actB;
    unsigned short* A1 = (unsigned short*)(ws + off);  off += actB;
    unsigned short* Cb = (unsigned short*)(ws + off);  off += actB;

    int nb = (N + 255) / 256, eb = (E + 255) / 256;

    // --- edge dtype detection ---
    k_flag_init<<<1, 64, 0, stream>>>(flag);
    k_flag_check<<<512, 256, 0, stream>>>((const long long*)eidx, E, (long long)N, flag);

    // --- CSR build ---
    k_zero_i32<<<nb, 256, 0, stream>>>(counts, N);
    k_count<<<eb, 256, 0, stream>>>(eidx, flag, counts, E);
    k_dinv<<<nb, 256, 0, stream>>>(counts, dinv, N);
    k_scan<<<1, 1024, 0, stream>>>(counts, starts, N);
    k_copy_i32<<<nb, 256, 0, stream>>>(starts, counts, N);
    k_fill<<<eb, 256, 0, stream>>>(eidx, flag, counts, srcs, E);

    // --- weight + input conversion ---
    k_cvt_w<<<256, 256, 0, stream>>>(W[0], Wh[0], Wl[0], FIN, H);
    for (int l = 1; l < 4; l++)
        k_cvt_w<<<256, 256, 0, stream>>>(W[l], Wh[l], Wl[l], H, H);
    k_cvt_x<<<1024, 256, 0, stream>>>(x, A0, (long long)N * FIN / 4);

    dim3 ggrid(2, (N + 127) / 128);
    int gb = (N + 3) / 4;

    // --- layer 1 ---
    k_gemm_mfma<<<ggrid, 256, 0, stream>>>(A0, Wh[0], Wl[0], Cb, N);
    k_gather_bf16<<<gb, 256, 0, stream>>>(Cb, srcs, starts, dinv, b[0], A1, N, H);
    // --- layer 2 ---
    k_gemm_mfma<<<ggrid, 256, 0, stream>>>(A1, Wh[1], Wl[1], Cb, N);
    k_gather_bf16<<<gb, 256, 0, stream>>>(Cb, srcs, starts, dinv, b[1], A0, N, H);
    // --- layer 3 ---
    k_gemm_mfma<<<ggrid, 256, 0, stream>>>(A0, Wh[2], Wl[2], Cb, N);
    k_gather_bf16<<<gb, 256, 0, stream>>>(Cb, srcs, starts, dinv, b[2], A1, N, H);
    // --- layer 4 (fused log_softmax) ---
    k_gemm_mfma<<<ggrid, 256, 0, stream>>>(A1, Wh[3], Wl[3], Cb, N);
    k_gather_lsm<<<gb, 256, 0, stream>>>(Cb, srcs, starts, dinv, b[3],
                                         (float*)d_out, N, H);
}